// Round 7
// baseline (97.550 us; speedup 1.0000x reference)
//
#include <hip/hip_runtime.h>

// UOT mm_unbalanced(div='l2') on MI355X — two launches, wave-autonomous tiles.
// K = max(5a_i+5b_j - M_ij, 0); M ~ 40..300 while 5(a+b) ~ 4e-3 => K==0,
// plan collapses to 0 after iteration 1; loop exits at iteration 2.
// k_main: one WAVE per 32x32 tile (16384 tiles), per-wave LDS staging
// (fp32->bf16 + exact fp32 norms), bf16-MFMA screen with rigorous error
// bound Cw. ZERO barriers, zero cross-wave traffic: waves overlap freely
// (16 independent waves/CU). Fast path => closed-form err; cold path =>
// exact iteration-1 (fp32 re-dot inside the error band). Outputs per-tile
// disjoint (no pre-zero of poisoned ws).
// k_tail: int4 bitmap scan; degenerate => block 0 writes outputs; general
// => persistent loop (<=1000 iters) with sense-reversing barrier (cold).

#define NV 4096
#define RM 5.0f
#define EPSF 1e-16f
#define STOP2 1e-30f   // (1e-15)^2
#define NITER 1000
#define MAGIC 0x5a17c0de
#define GRID_T 512
#define NT 16384       // number of 32x32 tiles (128 x 128 grid)

// W float offsets (producer-writes-before-consumer-reads; no pre-zero)
#define ERRT_OFF 0        // [16384] per-tile err^2, current level
#define ERRS_OFF 16384    // scalar err^2
#define OTP_OFF  32768    // [16384] per-tile ot partials
#define RSP_OFF  49152    // [16384][32] per-tile rowsums
#define CSP_OFF  573440   // [16384][32] per-tile colsums
#define RS_OFF   1097728  // [4096] reduced rowsums (current level)
#define CS_OFF   1101824  // [4096] reduced colsums
#define BMI_OFF  1105920  // int [16384] tile-nonzero bitmap (16B aligned)
#define CTL_OFF  1122304  // int [cnt, sense, magic]
#define G_OFF    1126400  // [4096*4096] plan

typedef short bf16x8 __attribute__((ext_vector_type(8)));
typedef float f32x4  __attribute__((ext_vector_type(4)));
typedef unsigned short u16;

__device__ __forceinline__ float wave_sum_all(float v) {
  #pragma unroll
  for (int off = 1; off < 64; off <<= 1) v += __shfl_xor(v, off);
  return v;
}
__device__ __forceinline__ float red32_sum(float v) {
  #pragma unroll
  for (int off = 1; off < 32; off <<= 1) v += __shfl_xor(v, off);
  return v;
}
__device__ __forceinline__ float red32_max(float v) {
  #pragma unroll
  for (int off = 1; off < 32; off <<= 1) v = fmaxf(v, __shfl_xor(v, off));
  return v;
}
__device__ __forceinline__ float red16_sum(float v) {  // over lrow bits
  v += __shfl_xor(v, 1); v += __shfl_xor(v, 2);
  v += __shfl_xor(v, 4); v += __shfl_xor(v, 8);
  return v;
}
// output reduction kept bit-identical to validated rounds
__device__ __forceinline__ float wave_sum_dn(float v) {
  #pragma unroll
  for (int off = 32; off; off >>= 1) v += __shfl_down(v, off);
  return v;
}
__device__ __forceinline__ float dot64(const float* __restrict__ xr,
                                       const float* __restrict__ yr) {
  float d = 0.f;
  #pragma unroll 1
  for (int k = 0; k < 64; ++k) d = fmaf(xr[k], yr[k], d);
  return d;
}
__device__ __forceinline__ unsigned pack2(float x, float y) {
  return (__float_as_uint(x) >> 16) | (__float_as_uint(y) & 0xffff0000u);
}

// Per-WAVE stage: 32 rows x 64 fp32 -> bf16 LDS [32][72] + exact fp32 norms.
// 8 independent coalesced float4 loads/lane; wave-internal only (no barrier:
// LDS ops of one wave complete in order).
__device__ __forceinline__ void stage32(const float* __restrict__ src,
                                        u16 (*dst)[72], float* nrm, int lane) {
  #pragma unroll
  for (int it = 0; it < 8; ++it) {
    const int flat = lane + it * 64;        // float4 slot: 16 per row
    const int r = flat >> 4, c4 = flat & 15;
    const float4 v = *(const float4*)(src + (size_t)r * 64 + c4 * 4);
    float p = fmaf(v.x, v.x, fmaf(v.y, v.y, fmaf(v.z, v.z, v.w * v.w)));
    p += __shfl_xor(p, 1); p += __shfl_xor(p, 2);
    p += __shfl_xor(p, 4); p += __shfl_xor(p, 8);
    if (c4 == 0) nrm[r] = p;                // exact fp32 ||row||^2
    uint2 w;
    w.x = pack2(v.x, v.y);
    w.y = pack2(v.z, v.w);
    *(uint2*)&dst[r][c4 * 4] = w;
  }
}

// 32x32 bf16 dot tile for ONE wave: 2x2 frags of 16x16, K=64 in two steps.
__device__ __forceinline__ void dots32(const u16 (*As)[72], const u16 (*Bs)[72],
                                       int lane, f32x4 acc[2][2]) {
  const int lrow = lane & 15, lk8 = lane >> 4;
  #pragma unroll
  for (int i = 0; i < 2; ++i)
    #pragma unroll
    for (int j = 0; j < 2; ++j)
      acc[i][j] = (f32x4){0.f, 0.f, 0.f, 0.f};
  #pragma unroll
  for (int ks = 0; ks < 2; ++ks) {
    bf16x8 af[2], bg[2];
    #pragma unroll
    for (int f = 0; f < 2; ++f) {
      af[f] = *(const bf16x8*)&As[f * 16 + lrow][ks * 32 + lk8 * 8];
      bg[f] = *(const bf16x8*)&Bs[f * 16 + lrow][ks * 32 + lk8 * 8];
    }
    #pragma unroll
    for (int fr = 0; fr < 2; ++fr)
      #pragma unroll
      for (int fc = 0; fc < 2; ++fc)
        acc[fr][fc] = __builtin_amdgcn_mfma_f32_16x16x32_bf16(
            af[fr], bg[fc], acc[fr][fc], 0, 0, 0);
  }
}

// sense-reversing device barrier (general/cold path only)
__device__ __forceinline__ void gbar(int* ctl) {
  __threadfence();
  __syncthreads();
  if (threadIdx.x == 0) {
    while (__hip_atomic_load(&ctl[2], __ATOMIC_ACQUIRE,
                             __HIP_MEMORY_SCOPE_AGENT) != (int)MAGIC)
      __builtin_amdgcn_s_sleep(8);
    const int sense = __hip_atomic_load(&ctl[1], __ATOMIC_ACQUIRE,
                                        __HIP_MEMORY_SCOPE_AGENT);
    const int old = __hip_atomic_fetch_add(&ctl[0], 1, __ATOMIC_ACQ_REL,
                                           __HIP_MEMORY_SCOPE_AGENT);
    if (old == GRID_T - 1) {
      __hip_atomic_store(&ctl[0], 0, __ATOMIC_RELAXED, __HIP_MEMORY_SCOPE_AGENT);
      __hip_atomic_store(&ctl[1], sense ^ 1, __ATOMIC_RELEASE,
                         __HIP_MEMORY_SCOPE_AGENT);
    } else {
      while (__hip_atomic_load(&ctl[1], __ATOMIC_ACQUIRE,
                               __HIP_MEMORY_SCOPE_AGENT) == sense)
        __builtin_amdgcn_s_sleep(16);
    }
  }
  __syncthreads();
  __threadfence();
}

// ======================= k_main: iteration 1, barrier-free =============
__global__ __launch_bounds__(256, 4) void k_main(
    const float* __restrict__ X, const float* __restrict__ Y,
    const float* __restrict__ a, const float* __restrict__ b,
    float* __restrict__ W) {
  __shared__ u16 Aw[4][32][72], Bw[4][32][72];
  __shared__ float X2w[4][32], Y2w[4][32];

  const int tid = threadIdx.x, lane = tid & 63, wv = tid >> 6;
  const int lrow = lane & 15, lk8 = lane >> 4, l32 = lane & 31;
  const int t = blockIdx.x * 4 + wv;        // wave-owned 32x32 tile
  const int by = t >> 7, bx = t & 127;
  const int r0 = by * 32, c0 = bx * 32;
  int* bmi = (int*)(W + BMI_OFF);
  float* Gp = W + G_OFF;

  const float av = a[r0 + l32];             // issue early, overlap staging
  const float bv = b[c0 + l32];

  stage32(X + (size_t)r0 * 64, Aw[wv], X2w[wv], lane);
  stage32(Y + (size_t)c0 * 64, Bw[wv], Y2w[wv], lane);

  f32x4 acc[2][2];
  dots32(Aw[wv], Bw[wv], lane, acc);

  float x2r[8], y2c[2];
  #pragma unroll
  for (int fr = 0; fr < 2; ++fr)
    #pragma unroll
    for (int j = 0; j < 4; ++j)
      x2r[fr * 4 + j] = X2w[wv][fr * 16 + lk8 * 4 + j];
  #pragma unroll
  for (int fc = 0; fc < 2; ++fc)
    y2c[fc] = Y2w[wv][fc * 16 + lrow];

  const float x2lv = X2w[wv][l32], y2lv = Y2w[wv][l32];
  const float amax = red32_max(av), bmax = red32_max(bv);
  const float x2m = red32_max(x2lv), y2m = red32_max(y2lv);
  // bf16-dot error bound: |2*dot~-2*dot| <= ~0.016*sqrt(x2m*y2m); Cw adds
  // the K>0 threshold 5(a+b) and slack. M~ >= Cw  =>  K == 0 certainly.
  const float Cw = RM * (amax + bmax) + 0.02f * sqrtf(x2m * y2m) + 0.05f;

  float mmin = 3.4e38f;
  #pragma unroll
  for (int fr = 0; fr < 2; ++fr)
    #pragma unroll
    for (int j = 0; j < 4; ++j)
      #pragma unroll
      for (int fc = 0; fc < 2; ++fc)
        mmin = fminf(mmin,
                     fmaf(-2.f, acc[fr][fc][j], x2r[fr * 4 + j] + y2c[fc]));

  if (__ballot(mmin < Cw) == 0ull) {
    // entire tile K==0 => G1==0; err contrib = (sum a^2)(sum b^2)
    const float Ea = red32_sum(av * av);
    const float Eb = red32_sum(bv * bv);
    if (lane == 0) {
      W[ERRT_OFF + t] = Ea * Eb;
      bmi[t] = 0;
    }
    return;
  }

  // ---- cold: exact iteration-1 for this tile ----
  float sa = 0.f, sb = 0.f;
  for (int i = lane; i < NV; i += 64) { sa += a[i]; sb += b[i]; }
  sa = wave_sum_all(sa); sb = wave_sum_all(sb);
  float bcf[2], gdc[2];
  #pragma unroll
  for (int fc = 0; fc < 2; ++fc) {
    bcf[fc] = __shfl(bv, fc * 16 + lrow);
    gdc[fc] = RM * bcf[fc] * sa;
  }
  float errp = 0.f, csum[2] = {0.f, 0.f};
  int nzl = 0;
  float rs8[8];
  #pragma unroll
  for (int fr = 0; fr < 2; ++fr)
    #pragma unroll
    for (int j = 0; j < 4; ++j) {
      const int ridx = fr * 16 + lk8 * 4 + j;
      const float ar = __shfl(av, ridx);
      const float gdr = RM * ar * sb;
      const int grow = r0 + ridx;
      float rsum = 0.f;
      #pragma unroll
      for (int fc = 0; fc < 2; ++fc) {
        float Mv = fmaf(-2.f, acc[fr][fc][j], x2r[fr * 4 + j] + y2c[fc]);
        if (Mv < Cw) {   // inside error band: exact fp32 re-dot
          const float dx = dot64(X + ((size_t)grow << 6),
                                 Y + ((size_t)(c0 + fc * 16 + lrow) << 6));
          Mv = x2r[fr * 4 + j] + y2c[fc] - 2.f * dx;
        }
        Mv = fmaxf(Mv, 0.f);
        const float Kv = fmaxf(RM * (ar + bcf[fc]) - Mv, 0.f);
        const float g0 = ar * bcf[fc];
        const float g = Kv * g0 / (gdr + gdc[fc] + EPSF);
        acc[fr][fc][j] = g;
        const float dl = g - g0;
        errp += dl * dl;
        nzl |= (g != 0.f);
        rsum += g;
        csum[fc] += g;
      }
      rs8[fr * 4 + j] = red16_sum(rsum);   // rowsum over 32 cols
    }
  const int nz = (__ballot(nzl) != 0ull) ? 1 : 0;
  if (nz) {
    #pragma unroll
    for (int fr = 0; fr < 2; ++fr)
      #pragma unroll
      for (int j = 0; j < 4; ++j) {
        const int ridx = fr * 16 + lk8 * 4 + j;
        const int grow = r0 + ridx;
        #pragma unroll
        for (int fc = 0; fc < 2; ++fc)
          Gp[(size_t)grow * NV + c0 + fc * 16 + lrow] = acc[fr][fc][j];
        if (lrow == 0) W[RSP_OFF + (size_t)t * 32 + ridx] = rs8[fr * 4 + j];
      }
    #pragma unroll
    for (int fc = 0; fc < 2; ++fc) {
      float cv = csum[fc];
      cv += __shfl_xor(cv, 16); cv += __shfl_xor(cv, 32);
      if (lane < 16) W[CSP_OFF + (size_t)t * 32 + fc * 16 + lrow] = cv;
    }
  }
  errp = wave_sum_all(errp);
  if (lane == 0) {
    W[ERRT_OFF + t] = errp;
    bmi[t] = nz;
  }
}

// ======================= k_tail: steer + general =======================
__global__ __launch_bounds__(256, 2) void k_tail(
    const float* __restrict__ X, const float* __restrict__ Y,
    const float* __restrict__ a, const float* __restrict__ b,
    float* __restrict__ W, float* __restrict__ out) {
  __shared__ u16 Aw[4][32][72], Bw[4][32][72];
  __shared__ float X2w[4][32], Y2w[4][32];
  __shared__ float serr[4], sred[4];
  __shared__ int s_any;

  const int bid = blockIdx.x, tid = threadIdx.x;
  const int lane = tid & 63, wv = tid >> 6;
  const int lrow = lane & 15, lk8 = lane >> 4, l32 = lane & 31;
  float* Gp = W + G_OFF;
  int* bmi = (int*)(W + BMI_OFF);
  int* ctl = (int*)(W + CTL_OFF);

  if (bid == 0 && tid == 0) {   // arm barrier (general path only)
    __hip_atomic_store(&ctl[0], 0, __ATOMIC_RELAXED, __HIP_MEMORY_SCOPE_AGENT);
    __hip_atomic_store(&ctl[1], 0, __ATOMIC_RELAXED, __HIP_MEMORY_SCOPE_AGENT);
    __hip_atomic_store(&ctl[2], (int)MAGIC, __ATOMIC_RELEASE,
                       __HIP_MEMORY_SCOPE_AGENT);
  }

  // vectorized bitmap scan: 16384 ints as 4096 int4
  const int4* bmi4 = (const int4*)bmi;
  int orv = 0;
  for (int i = tid; i < 4096; i += 256) {
    const int4 q = bmi4[i];
    orv |= q.x | q.y | q.z | q.w;
  }
  if (tid == 0) s_any = 0;
  __syncthreads();
  if (orv) s_any = 1;
  __syncthreads();

  if (!s_any) {
    // plan identically 0: ot=0, marginal_loss = mean(a^2)
    if (bid == 0) {
      float s = 0.f;
      for (int i = tid; i < NV; i += 256) { const float d = a[i]; s = fmaf(d, d, s); }
      s = wave_sum_dn(s);
      if (lane == 0) serr[wv] = s;
      __syncthreads();
      if (tid == 0) {
        out[0] = 0.f;
        out[1] = (serr[0] + serr[1] + serr[2] + serr[3]) * (1.0f / (float)NV);
      }
    }
    return;
  }

  // ---------------- general path (cold; correctness-first) -------------
  int p = 2;
  while (true) {
    // reduce per-tile partials -> RS/CS; rows/cols bid*8..+8 owned here
    {
      const int sr = tid >> 5, j32 = tid & 31;
      const int r = bid * 8 + sr;
      const int byt = r >> 5, rl = r & 31;
      float vs = 0.f;
      for (int k = j32; k < 128; k += 32) {
        const int tt2 = byt * 128 + k;
        vs += bmi[tt2] ? W[RSP_OFF + (size_t)tt2 * 32 + rl] : 0.f;
      }
      vs = red32_sum(vs);
      if (j32 == 0) W[RS_OFF + r] = vs;
      float cs = 0.f;
      for (int k = j32; k < 128; k += 32) {
        const int tt2 = k * 128 + byt;      // tile (by=k, bx=byt)
        cs += bmi[tt2] ? W[CSP_OFF + (size_t)tt2 * 32 + rl] : 0.f;
      }
      cs = red32_sum(cs);
      if (j32 == 0) W[CS_OFF + r] = cs;
    }
    if (bid == 0) {
      float e = 0.f;
      for (int i = tid; i < NT; i += 256) e += W[ERRT_OFF + i];
      e = wave_sum_all(e);
      if (lane == 0) sred[wv] = e;
      __syncthreads();
      if (tid == 0) W[ERRS_OFF] = sred[0] + sred[1] + sred[2] + sred[3];
    }
    gbar(ctl);
    const float errv = W[ERRS_OFF];
    if (errv <= STOP2 || p > NITER) break;

    #pragma unroll 1
    for (int tt = 0; tt < 8; ++tt) {
      const int t = bid * 4 + wv + tt * 2048;
      if (!bmi[t]) { if (lane == 0) W[ERRT_OFF + t] = 0.f; continue; }
      const int by = t >> 7, bx = t & 127;
      const int r0 = by * 32, c0 = bx * 32;

      const float av = a[r0 + l32], bv = b[c0 + l32];
      const float Rv = W[RS_OFF + r0 + l32], Cv = W[CS_OFF + c0 + l32];

      stage32(X + (size_t)r0 * 64, Aw[wv], X2w[wv], lane);
      stage32(Y + (size_t)c0 * 64, Bw[wv], Y2w[wv], lane);
      f32x4 acc[2][2];
      dots32(Aw[wv], Bw[wv], lane, acc);

      float x2r[8], y2c[2], bcf[2], Ccf[2];
      #pragma unroll
      for (int fr = 0; fr < 2; ++fr)
        #pragma unroll
        for (int j = 0; j < 4; ++j)
          x2r[fr * 4 + j] = X2w[wv][fr * 16 + lk8 * 4 + j];
      #pragma unroll
      for (int fc = 0; fc < 2; ++fc) {
        y2c[fc] = Y2w[wv][fc * 16 + lrow];
        bcf[fc] = __shfl(bv, fc * 16 + lrow);
        Ccf[fc] = __shfl(Cv, fc * 16 + lrow);
      }
      const float x2lv = X2w[wv][l32], y2lv = Y2w[wv][l32];
      const float amax = red32_max(av), bmax = red32_max(bv);
      const float x2m = red32_max(x2lv), y2m = red32_max(y2lv);
      const float Cw = RM * (amax + bmax) + 0.02f * sqrtf(x2m * y2m) + 0.05f;

      float errp = 0.f, csum[2] = {0.f, 0.f};
      int nzl = 0;
      float rs8[8];
      #pragma unroll
      for (int fr = 0; fr < 2; ++fr)
        #pragma unroll
        for (int j = 0; j < 4; ++j) {
          const int ridx = fr * 16 + lk8 * 4 + j;
          const float ar = __shfl(av, ridx);
          const float Rr = __shfl(Rv, ridx);
          const int grow = r0 + ridx;
          float rsum = 0.f;
          #pragma unroll
          for (int fc = 0; fc < 2; ++fc) {
            const int gcol = c0 + fc * 16 + lrow;
            const float g = Gp[(size_t)grow * NV + gcol];
            float Mv = fmaf(-2.f, acc[fr][fc][j], x2r[fr * 4 + j] + y2c[fc]);
            if (Mv < Cw) {
              const float dx = dot64(X + ((size_t)grow << 6),
                                     Y + ((size_t)gcol << 6));
              Mv = x2r[fr * 4 + j] + y2c[fc] - 2.f * dx;
            }
            Mv = fmaxf(Mv, 0.f);
            const float Kv = fmaxf(RM * (ar + bcf[fc]) - Mv, 0.f);
            const float gd = RM * Rr + RM * Ccf[fc] + EPSF;
            const float gn = Kv * g / gd;
            acc[fr][fc][j] = gn;
            const float dl = gn - g;
            errp += dl * dl;
            nzl |= (gn != 0.f);
            rsum += gn;
            csum[fc] += gn;
          }
          rs8[fr * 4 + j] = red16_sum(rsum);
        }
      const int nz = (__ballot(nzl) != 0ull) ? 1 : 0;
      #pragma unroll
      for (int fr = 0; fr < 2; ++fr)
        #pragma unroll
        for (int j = 0; j < 4; ++j) {
          const int ridx = fr * 16 + lk8 * 4 + j;
          const int grow = r0 + ridx;
          #pragma unroll
          for (int fc = 0; fc < 2; ++fc)
            Gp[(size_t)grow * NV + c0 + fc * 16 + lrow] = acc[fr][fc][j];
          if (lrow == 0) W[RSP_OFF + (size_t)t * 32 + ridx] = rs8[fr * 4 + j];
        }
      #pragma unroll
      for (int fc = 0; fc < 2; ++fc) {
        float cv = csum[fc];
        cv += __shfl_xor(cv, 16); cv += __shfl_xor(cv, 32);
        if (lane < 16) W[CSP_OFF + (size_t)t * 32 + fc * 16 + lrow] = cv;
      }
      errp = wave_sum_all(errp);
      if (lane == 0) {
        W[ERRT_OFF + t] = errp;
        bmi[t] = nz;
      }
    }
    gbar(ctl);
    ++p;
  }

  // final: ot = sum(G*M) over nonzero tiles (exact dots); marg = RS
  #pragma unroll 1
  for (int tt = 0; tt < 8; ++tt) {
    const int t = bid * 4 + wv + tt * 2048;
    float otw = 0.f;
    if (bmi[t]) {
      const int by = t >> 7, bx = t & 127;
      const int r0 = by * 32, c0 = bx * 32;
      float otp = 0.f;
      #pragma unroll
      for (int fr = 0; fr < 2; ++fr)
        #pragma unroll
        for (int j = 0; j < 4; ++j) {
          const int grow = r0 + fr * 16 + lk8 * 4 + j;
          #pragma unroll
          for (int fc = 0; fc < 2; ++fc) {
            const int gcol = c0 + fc * 16 + lrow;
            const float g = Gp[(size_t)grow * NV + gcol];
            if (g != 0.f) {
              const float* xr = X + ((size_t)grow << 6);
              const float* yr = Y + ((size_t)gcol << 6);
              const float dd = dot64(xr, yr);
              const float x2 = dot64(xr, xr);
              const float y2 = dot64(yr, yr);
              otp += g * fmaxf(x2 + y2 - 2.f * dd, 0.f);
            }
          }
        }
      otw = wave_sum_all(otp);
    }
    if (lane == 0) W[OTP_OFF + t] = otw;
  }
  gbar(ctl);
  if (bid == 0) {
    float so = 0.f;
    for (int i = tid; i < NT; i += 256) so += W[OTP_OFF + i];
    so = wave_sum_dn(so);
    float sm = 0.f;
    for (int i = tid; i < NV; i += 256) {
      const float d = W[RS_OFF + i] - a[i];
      sm = fmaf(d, d, sm);
    }
    sm = wave_sum_dn(sm);
    if (lane == 0) { sred[wv] = so; serr[wv] = sm; }
    __syncthreads();
    if (tid == 0) {
      out[0] = sred[0] + sred[1] + sred[2] + sred[3];
      out[1] = (serr[0] + serr[1] + serr[2] + serr[3]) * (1.0f / (float)NV);
    }
  }
}

extern "C" void kernel_launch(void* const* d_in, const int* in_sizes, int n_in,
                              void* d_out, int out_size, void* d_ws, size_t ws_size,
                              hipStream_t stream) {
  const float* X = (const float*)d_in[0];   // source [4096,64]
  const float* Y = (const float*)d_in[1];   // target [4096,64]
  const float* a = (const float*)d_in[2];   // source_density [4096]
  const float* b = (const float*)d_in[3];   // target_density [4096]
  float* out = (float*)d_out;               // [ot_loss, marginal_loss]
  float* W = (float*)d_ws;

  k_main<<<NT / 4, 256, 0, stream>>>(X, Y, a, b, W);
  k_tail<<<GRID_T, 256, 0, stream>>>(X, Y, a, b, W, out);
}

// Round 8
// 92.982 us; speedup vs baseline: 1.0491x; 1.0491x over previous
//
#include <hip/hip_runtime.h>

// UOT mm_unbalanced(div='l2') on MI355X — profile-bound screen, 3 launches.
// K = max(5a_i+5b_j - M_ij, 0). Screen: per-group Cauchy-Schwarz with 16
// groups of 4 dims: M_ij >= X2_i + Y2_j - 2<u_i,v_j> (u,v = 16-dim norm
// profiles). Bound value ~4.3 vs threshold 5(a+b)+margin ~0.014 => zero
// suspects for gaussian data; any suspect pair is recomputed EXACTLY in
// fp32 (cold), so correctness never depends on the data. Degenerate case
// (all K==0): plan==0 after iter 1, loop exits at iter 2, ot=0,
// marginal_loss=mean(a^2).
// k_prof: profiles+norms+group stats (coalesced 2MB). k_screen: 16-dim
// dot screen, pure VALU, no LDS. k_tail: nsus==0 => output; else full
// exact iteration-1 for suspect tiles + persistent general loop (cold).

#define NV 4096
#define RM 5.0f
#define EPSF 1e-16f
#define STOP2 1e-30f   // (1e-15)^2
#define NITER 1000
#define MAGIC 0x5a17c0de
#define GRID_T 512
#define NT 16384       // 32x32 tiles (128 x 128)
#define MARGIN 1e-2f   // covers ref-M fp32 error (~4e-4) + screen fp error (~1e-4)

// W float offsets (producer-writes-before-consumer-reads; no pre-zero)
#define UP_OFF   0        // U profiles [4096][16]
#define VP_OFF   65536    // V profiles [4096][16]
#define X2_OFF   131072   // [4096] row sumsq (fp32)
#define Y2_OFF   135168   // [4096]
#define RA2_OFF  139264   // [128] per-32-row sum a^2
#define CB2_OFF  139392   // [128] per-32-col sum b^2
#define PA_OFF   139520   // [128] per-32-row sum a
#define PB_OFF   139648   // [128] per-32-col sum b
#define ERRT_OFF 147456   // [16384] per-tile err^2
#define ERRS_OFF 163840   // scalar err^2
#define OTP_OFF  180224   // [16384] per-tile ot partials
#define RSP_OFF  196608   // [16384][32] per-tile rowsums
#define CSP_OFF  720896   // [16384][32] per-tile colsums
#define RS_OFF   1245184  // [4096] reduced rowsums
#define CS_OFF   1249280  // [4096] reduced colsums
#define BMI_OFF  1253376  // int [16384] tile-nonzero bitmap
#define SUS_OFF  1269760  // int [16384] tile-suspect flags
#define NSUS_OFF 1286144  // int [0]=nsus, [1]=cnt, [2]=sense, [3]=magic
#define G_OFF    1310720  // [4096*4096] plan

typedef short bf16x8 __attribute__((ext_vector_type(8)));
typedef float f32x4  __attribute__((ext_vector_type(4)));
typedef unsigned short u16;

__device__ __forceinline__ float wave_sum_all(float v) {
  #pragma unroll
  for (int off = 1; off < 64; off <<= 1) v += __shfl_xor(v, off);
  return v;
}
__device__ __forceinline__ float red32_sum(float v) {
  #pragma unroll
  for (int off = 1; off < 32; off <<= 1) v += __shfl_xor(v, off);
  return v;
}
__device__ __forceinline__ float red32_max(float v) {
  #pragma unroll
  for (int off = 1; off < 32; off <<= 1) v = fmaxf(v, __shfl_xor(v, off));
  return v;
}
// output reduction kept bit-identical to validated rounds
__device__ __forceinline__ float wave_sum_dn(float v) {
  #pragma unroll
  for (int off = 32; off; off >>= 1) v += __shfl_down(v, off);
  return v;
}
__device__ __forceinline__ float dot64(const float* __restrict__ xr,
                                       const float* __restrict__ yr) {
  float d = 0.f;
  #pragma unroll 1
  for (int k = 0; k < 64; ++k) d = fmaf(xr[k], yr[k], d);
  return d;
}
__device__ __forceinline__ unsigned pack2(float x, float y) {
  return (__float_as_uint(x) >> 16) | (__float_as_uint(y) & 0xffff0000u);
}

// ================= k_prof: profiles + norms + group stats ================
// 256 blocks x 256. Block b: combined rows b*32..+32 (0..4095 = X, rest Y).
// Wave handles 8 rows; lane l: row l>>3, dims (l&7)*8..+8 = groups 2(l&7),
// 2(l&7)+1 (4 dims each). Fully coalesced 16B/lane reads.
__global__ __launch_bounds__(256) void k_prof(
    const float* __restrict__ X, const float* __restrict__ Y,
    const float* __restrict__ a, const float* __restrict__ bden,
    float* __restrict__ W) {
  const int bid = blockIdx.x, tid = threadIdx.x;
  const int lane = tid & 63, wvq = tid >> 6;
  const int lr = lane >> 3, l8 = lane & 7;
  const int R = bid * 32 + wvq * 8 + lr;         // combined row 0..8191
  const bool isX = (R < NV);
  const int row = isX ? R : R - NV;
  const float* src = (isX ? X : Y) + (size_t)row * 64;
  float* UPo = W + (isX ? UP_OFF : VP_OFF) + (size_t)row * 16;

  const float4 v0 = *(const float4*)(src + l8 * 8);
  const float4 v1 = *(const float4*)(src + l8 * 8 + 4);
  const float s0 = fmaf(v0.x, v0.x, fmaf(v0.y, v0.y, fmaf(v0.z, v0.z, v0.w * v0.w)));
  const float s1 = fmaf(v1.x, v1.x, fmaf(v1.y, v1.y, fmaf(v1.z, v1.z, v1.w * v1.w)));
  float2 uq; uq.x = sqrtf(s0); uq.y = sqrtf(s1);
  *(float2*)(UPo + l8 * 2) = uq;                 // profile groups 2*l8, +1
  float st = s0 + s1;
  st += __shfl_xor(st, 1); st += __shfl_xor(st, 2); st += __shfl_xor(st, 4);
  if (l8 == 0) W[(isX ? X2_OFF : Y2_OFF) + row] = st;

  // per-32-group stats of a (blocks 0..127) / b (128..255)
  if (wvq == 0 && lane < 32) {
    if (bid < 128) {
      const float av = a[bid * 32 + lane];
      const float r2 = red32_sum(av * av);
      const float pa = red32_sum(av);
      if (lane == 0) { W[RA2_OFF + bid] = r2; W[PA_OFF + bid] = pa; }
    } else {
      const float bv = bden[(bid - 128) * 32 + lane];
      const float c2 = red32_sum(bv * bv);
      const float pb = red32_sum(bv);
      if (lane == 0) { W[CB2_OFF + (bid - 128)] = c2; W[PB_OFF + (bid - 128)] = pb; }
    }
  }
  // zero suspect flags + counter (d_ws is poisoned each launch)
  if (tid < 64) ((int*)(W + SUS_OFF))[bid * 64 + tid] = 0;
  if (bid == 0 && tid == 64) ((int*)(W + NSUS_OFF))[0] = 0;
}

// ================= k_screen: 16-dim profile screen =====================
// 512 blocks x 256. Block: 8 U-rows (u[8][16] in VGPRs); wave: 1024-col
// span; lane: 2 cols x 8 passes. Pure VALU; suspect => atomics (cold).
// Non-suspect pair certifies: P = X2+Y2-2<u,v> >= 5(a+b)+MARGIN => K==0
// in the reference too (MARGIN >> both sides' fp32 error).
__global__ __launch_bounds__(256, 2) void k_screen(
    const float* __restrict__ a, const float* __restrict__ bden,
    float* __restrict__ W) {
  const int tid = threadIdx.x, lane = tid & 63, wv = tid >> 6;
  const int rbase = blockIdx.x * 8;
  const int cbase = wv * 1024;
  const float* UP = W + UP_OFF;
  const float* VP = W + VP_OFF;
  int* sus  = (int*)(W + SUS_OFF);
  int* nsus = (int*)(W + NSUS_OFF);

  float u[8][16], ga[8];
  #pragma unroll
  for (int r = 0; r < 8; ++r) {
    const int row = rbase + r;
    #pragma unroll
    for (int q = 0; q < 4; ++q) {
      const float4 f = *(const float4*)(UP + (size_t)row * 16 + q * 4);
      u[r][q*4+0] = f.x; u[r][q*4+1] = f.y; u[r][q*4+2] = f.z; u[r][q*4+3] = f.w;
    }
    ga[r] = W[X2_OFF + row] - RM * a[row] - MARGIN;
  }

  #pragma unroll 1
  for (int k = 0; k < 8; ++k) {
    const int col0 = cbase + lane * 2 + k * 128;
    const float* vp = VP + (size_t)col0 * 16;
    float v0[16], v1[16];
    #pragma unroll
    for (int q = 0; q < 4; ++q) {
      const float4 f0 = *(const float4*)(vp + q * 4);
      const float4 f1 = *(const float4*)(vp + 16 + q * 4);
      v0[q*4+0] = f0.x; v0[q*4+1] = f0.y; v0[q*4+2] = f0.z; v0[q*4+3] = f0.w;
      v1[q*4+0] = f1.x; v1[q*4+1] = f1.y; v1[q*4+2] = f1.z; v1[q*4+3] = f1.w;
    }
    const float d0 = W[Y2_OFF + col0]     - RM * bden[col0];
    const float d1 = W[Y2_OFF + col0 + 1] - RM * bden[col0 + 1];

    unsigned smask = 0u;
    #pragma unroll
    for (int r = 0; r < 8; ++r) {
      float s0 = 0.f, s1 = 0.f;
      #pragma unroll
      for (int g = 0; g < 16; ++g) {
        s0 = fmaf(u[r][g], v0[g], s0);
        s1 = fmaf(u[r][g], v1[g], s1);
      }
      smask |= (2.f * s0 > ga[r] + d0) ? (1u << r) : 0u;
      smask |= (2.f * s1 > ga[r] + d1) ? (1u << (r + 8)) : 0u;
    }
    if (__builtin_expect(smask != 0u, 0)) {   // ~never: exact path handles
      #pragma unroll 1
      for (int r = 0; r < 8; ++r) {
        if (smask & (1u << r)) {
          atomicOr(&sus[((rbase + r) >> 5) * 128 + (col0 >> 5)], 1);
          atomicAdd(nsus, 1);
        }
        if (smask & (1u << (r + 8))) {
          atomicOr(&sus[((rbase + r) >> 5) * 128 + ((col0 + 1) >> 5)], 1);
          atomicAdd(nsus, 1);
        }
      }
    }
  }
}

// ---------- helpers for the cold general path (from validated r7) -------
__device__ __forceinline__ void stage32(const float* __restrict__ src,
                                        u16 (*dst)[72], float* nrm, int lane) {
  #pragma unroll
  for (int it = 0; it < 8; ++it) {
    const int flat = lane + it * 64;
    const int r = flat >> 4, c4 = flat & 15;
    const float4 v = *(const float4*)(src + (size_t)r * 64 + c4 * 4);
    float p = fmaf(v.x, v.x, fmaf(v.y, v.y, fmaf(v.z, v.z, v.w * v.w)));
    p += __shfl_xor(p, 1); p += __shfl_xor(p, 2);
    p += __shfl_xor(p, 4); p += __shfl_xor(p, 8);
    if (c4 == 0) nrm[r] = p;
    uint2 w;
    w.x = pack2(v.x, v.y);
    w.y = pack2(v.z, v.w);
    *(uint2*)&dst[r][c4 * 4] = w;
  }
}
__device__ __forceinline__ void dots32(const u16 (*As)[72], const u16 (*Bs)[72],
                                       int lane, f32x4 acc[2][2]) {
  const int lrow = lane & 15, lk8 = lane >> 4;
  #pragma unroll
  for (int i = 0; i < 2; ++i)
    #pragma unroll
    for (int j = 0; j < 2; ++j)
      acc[i][j] = (f32x4){0.f, 0.f, 0.f, 0.f};
  #pragma unroll
  for (int ks = 0; ks < 2; ++ks) {
    bf16x8 af[2], bg[2];
    #pragma unroll
    for (int f = 0; f < 2; ++f) {
      af[f] = *(const bf16x8*)&As[f * 16 + lrow][ks * 32 + lk8 * 8];
      bg[f] = *(const bf16x8*)&Bs[f * 16 + lrow][ks * 32 + lk8 * 8];
    }
    #pragma unroll
    for (int fr = 0; fr < 2; ++fr)
      #pragma unroll
      for (int fc = 0; fc < 2; ++fc)
        acc[fr][fc] = __builtin_amdgcn_mfma_f32_16x16x32_bf16(
            af[fr], bg[fc], acc[fr][fc], 0, 0, 0);
  }
}
// sense-reversing device barrier (cold path only); ctl[1]=cnt [2]=sense [3]=magic
__device__ __forceinline__ void gbar(int* ctl) {
  __threadfence();
  __syncthreads();
  if (threadIdx.x == 0) {
    while (__hip_atomic_load(&ctl[3], __ATOMIC_ACQUIRE,
                             __HIP_MEMORY_SCOPE_AGENT) != (int)MAGIC)
      __builtin_amdgcn_s_sleep(8);
    const int sense = __hip_atomic_load(&ctl[2], __ATOMIC_ACQUIRE,
                                        __HIP_MEMORY_SCOPE_AGENT);
    const int old = __hip_atomic_fetch_add(&ctl[1], 1, __ATOMIC_ACQ_REL,
                                           __HIP_MEMORY_SCOPE_AGENT);
    if (old == GRID_T - 1) {
      __hip_atomic_store(&ctl[1], 0, __ATOMIC_RELAXED, __HIP_MEMORY_SCOPE_AGENT);
      __hip_atomic_store(&ctl[2], sense ^ 1, __ATOMIC_RELEASE,
                         __HIP_MEMORY_SCOPE_AGENT);
    } else {
      while (__hip_atomic_load(&ctl[2], __ATOMIC_ACQUIRE,
                               __HIP_MEMORY_SCOPE_AGENT) == sense)
        __builtin_amdgcn_s_sleep(16);
    }
  }
  __syncthreads();
  __threadfence();
}

// ================= k_tail: steer + exact + general =====================
__global__ __launch_bounds__(256, 2) void k_tail(
    const float* __restrict__ X, const float* __restrict__ Y,
    const float* __restrict__ a, const float* __restrict__ bden,
    float* __restrict__ W, float* __restrict__ out) {
  __shared__ u16 Aw[4][32][72], Bw[4][32][72];
  __shared__ float X2w[4][32], Y2w[4][32];
  __shared__ float serr[4], sred[4];

  const int bid = blockIdx.x, tid = threadIdx.x;
  const int lane = tid & 63, wv = tid >> 6;
  const int lrow = lane & 15, lk8 = lane >> 4, l32 = lane & 31;
  float* Gp = W + G_OFF;
  int* bmi  = (int*)(W + BMI_OFF);
  int* sus  = (int*)(W + SUS_OFF);
  int* ctl  = (int*)(W + NSUS_OFF);

  // ---- hot gate: zero suspects => plan == 0 exactly ----
  if (ctl[0] == 0) {
    if (bid == 0) {
      float s = 0.f;
      for (int i = tid; i < NV; i += 256) { const float d = a[i]; s = fmaf(d, d, s); }
      s = wave_sum_dn(s);
      if (lane == 0) serr[wv] = s;
      __syncthreads();
      if (tid == 0) {
        out[0] = 0.f;
        out[1] = (serr[0] + serr[1] + serr[2] + serr[3]) * (1.0f / (float)NV);
      }
    }
    return;
  }

  // =================== cold: suspects exist ============================
  if (bid == 0 && tid == 0) {   // arm barrier
    __hip_atomic_store(&ctl[1], 0, __ATOMIC_RELAXED, __HIP_MEMORY_SCOPE_AGENT);
    __hip_atomic_store(&ctl[2], 0, __ATOMIC_RELAXED, __HIP_MEMORY_SCOPE_AGENT);
    __hip_atomic_store(&ctl[3], (int)MAGIC, __ATOMIC_RELEASE,
                       __HIP_MEMORY_SCOPE_AGENT);
  }

  // ---- exact iteration-1: suspect tiles exact, clean tiles closed-form
  #pragma unroll 1
  for (int tt = 0; tt < 8; ++tt) {
    const int t = bid * 4 + wv + tt * 2048;
    const int by = t >> 7, bx = t & 127;
    if (!sus[t]) {
      if (lane == 0) {
        W[ERRT_OFF + t] = W[RA2_OFF + by] * W[CB2_OFF + bx];
        bmi[t] = 0;
      }
      continue;
    }
    const int r0 = by * 32, c0 = bx * 32;
    const int cl = lane & 31, h = lane >> 5;   // lane: col cl, row-half h
    float sa = W[PA_OFF + lane] + W[PA_OFF + lane + 64];
    sa = wave_sum_all(sa);
    float sb = W[PB_OFF + lane] + W[PB_OFF + lane + 64];
    sb = wave_sum_all(sb);
    const float bcl = bden[c0 + cl];
    const float y2c = W[Y2_OFF + c0 + cl];
    const float* yr = Y + (size_t)(c0 + cl) * 64;
    float csum = 0.f, errp = 0.f;
    int nzl = 0;
    #pragma unroll 1
    for (int r = 0; r < 16; ++r) {
      const int row = r0 + h * 16 + r;
      const float ar = a[row];
      const float x2r = W[X2_OFF + row];
      const float dx = dot64(X + (size_t)row * 64, yr);
      const float Mv = fmaxf(x2r + y2c - 2.f * dx, 0.f);
      const float Kv = fmaxf(RM * (ar + bcl) - Mv, 0.f);
      const float g0 = ar * bcl;
      const float gd = RM * ar * sb + RM * bcl * sa + EPSF;
      const float g = Kv * g0 / gd;
      Gp[(size_t)row * NV + c0 + cl] = g;
      const float dl = g - g0;
      errp += dl * dl;
      nzl |= (g != 0.f);
      csum += g;
      float rsv = red32_sum(g);               // rowsum over the 32 cols
      if (cl == 0) W[RSP_OFF + (size_t)t * 32 + h * 16 + r] = rsv;
    }
    csum += __shfl_xor(csum, 32);             // combine both row-halves
    if (h == 0) W[CSP_OFF + (size_t)t * 32 + cl] = csum;
    errp = wave_sum_all(errp);
    const int nz = (__ballot(nzl) != 0ull) ? 1 : 0;
    if (lane == 0) { W[ERRT_OFF + t] = errp; bmi[t] = nz; }
  }
  gbar(ctl);

  // ---- persistent loop: p = 2 .. (validated r7 structure) ----
  int p = 2;
  while (true) {
    {
      const int sr = tid >> 5, j32 = tid & 31;
      const int r = bid * 8 + sr;
      const int byt = r >> 5, rl = r & 31;
      float vs = 0.f;
      for (int k = j32; k < 128; k += 32) {
        const int tt2 = byt * 128 + k;
        vs += bmi[tt2] ? W[RSP_OFF + (size_t)tt2 * 32 + rl] : 0.f;
      }
      vs = red32_sum(vs);
      if (j32 == 0) W[RS_OFF + r] = vs;
      float cs = 0.f;
      for (int k = j32; k < 128; k += 32) {
        const int tt2 = k * 128 + byt;
        cs += bmi[tt2] ? W[CSP_OFF + (size_t)tt2 * 32 + rl] : 0.f;
      }
      cs = red32_sum(cs);
      if (j32 == 0) W[CS_OFF + r] = cs;
    }
    if (bid == 0) {
      float e = 0.f;
      for (int i = tid; i < NT; i += 256) e += W[ERRT_OFF + i];
      e = wave_sum_all(e);
      if (lane == 0) sred[wv] = e;
      __syncthreads();
      if (tid == 0) W[ERRS_OFF] = sred[0] + sred[1] + sred[2] + sred[3];
    }
    gbar(ctl);
    const float errv = W[ERRS_OFF];
    if (errv <= STOP2 || p > NITER) break;

    #pragma unroll 1
    for (int tt = 0; tt < 8; ++tt) {
      const int t = bid * 4 + wv + tt * 2048;
      if (!bmi[t]) { if (lane == 0) W[ERRT_OFF + t] = 0.f; continue; }
      const int by = t >> 7, bx = t & 127;
      const int r0 = by * 32, c0 = bx * 32;

      const float av = a[r0 + l32], bv = bden[c0 + l32];
      const float Rv = W[RS_OFF + r0 + l32], Cv = W[CS_OFF + c0 + l32];

      stage32(X + (size_t)r0 * 64, Aw[wv], X2w[wv], lane);
      stage32(Y + (size_t)c0 * 64, Bw[wv], Y2w[wv], lane);
      f32x4 acc[2][2];
      dots32(Aw[wv], Bw[wv], lane, acc);

      float x2r[8], y2c[2], bcf[2], Ccf[2];
      #pragma unroll
      for (int fr = 0; fr < 2; ++fr)
        #pragma unroll
        for (int j = 0; j < 4; ++j)
          x2r[fr * 4 + j] = X2w[wv][fr * 16 + lk8 * 4 + j];
      #pragma unroll
      for (int fc = 0; fc < 2; ++fc) {
        y2c[fc] = Y2w[wv][fc * 16 + lrow];
        bcf[fc] = __shfl(bv, fc * 16 + lrow);
        Ccf[fc] = __shfl(Cv, fc * 16 + lrow);
      }
      const float x2lv = X2w[wv][l32], y2lv = Y2w[wv][l32];
      const float amax = red32_max(av), bmax = red32_max(bv);
      const float x2m = red32_max(x2lv), y2m = red32_max(y2lv);
      const float Cw = RM * (amax + bmax) + 0.02f * sqrtf(x2m * y2m) + 0.05f;

      float errp = 0.f, csum[2] = {0.f, 0.f};
      int nzl = 0;
      float rs8[8];
      #pragma unroll
      for (int fr = 0; fr < 2; ++fr)
        #pragma unroll
        for (int j = 0; j < 4; ++j) {
          const int ridx = fr * 16 + lk8 * 4 + j;
          const float ar = __shfl(av, ridx);
          const float Rr = __shfl(Rv, ridx);
          const int grow = r0 + ridx;
          float rsum = 0.f;
          #pragma unroll
          for (int fc = 0; fc < 2; ++fc) {
            const int gcol = c0 + fc * 16 + lrow;
            const float g = Gp[(size_t)grow * NV + gcol];
            float Mv = fmaf(-2.f, acc[fr][fc][j], x2r[fr * 4 + j] + y2c[fc]);
            if (Mv < Cw) {
              const float dx = dot64(X + ((size_t)grow << 6),
                                     Y + ((size_t)gcol << 6));
              Mv = x2r[fr * 4 + j] + y2c[fc] - 2.f * dx;
            }
            Mv = fmaxf(Mv, 0.f);
            const float Kv = fmaxf(RM * (ar + bcf[fc]) - Mv, 0.f);
            const float gd = RM * Rr + RM * Ccf[fc] + EPSF;
            const float gn = Kv * g / gd;
            acc[fr][fc][j] = gn;
            const float dl = gn - g;
            errp += dl * dl;
            nzl |= (gn != 0.f);
            rsum += gn;
            csum[fc] += gn;
          }
          float rv = rsum;
          rv += __shfl_xor(rv, 1); rv += __shfl_xor(rv, 2);
          rv += __shfl_xor(rv, 4); rv += __shfl_xor(rv, 8);
          rs8[fr * 4 + j] = rv;
        }
      const int nz = (__ballot(nzl) != 0ull) ? 1 : 0;
      #pragma unroll
      for (int fr = 0; fr < 2; ++fr)
        #pragma unroll
        for (int j = 0; j < 4; ++j) {
          const int ridx = fr * 16 + lk8 * 4 + j;
          const int grow = r0 + ridx;
          #pragma unroll
          for (int fc = 0; fc < 2; ++fc)
            Gp[(size_t)grow * NV + c0 + fc * 16 + lrow] = acc[fr][fc][j];
          if (lrow == 0) W[RSP_OFF + (size_t)t * 32 + ridx] = rs8[fr * 4 + j];
        }
      #pragma unroll
      for (int fc = 0; fc < 2; ++fc) {
        float cv = csum[fc];
        cv += __shfl_xor(cv, 16); cv += __shfl_xor(cv, 32);
        if (lane < 16) W[CSP_OFF + (size_t)t * 32 + fc * 16 + lrow] = cv;
      }
      errp = wave_sum_all(errp);
      if (lane == 0) {
        W[ERRT_OFF + t] = errp;
        bmi[t] = nz;
      }
    }
    gbar(ctl);
    ++p;
  }

  // final: ot = sum(G*M) over nonzero tiles (exact dots); marg = RS
  #pragma unroll 1
  for (int tt = 0; tt < 8; ++tt) {
    const int t = bid * 4 + wv + tt * 2048;
    float otw = 0.f;
    if (bmi[t]) {
      const int by = t >> 7, bx = t & 127;
      const int r0 = by * 32, c0 = bx * 32;
      float otp = 0.f;
      #pragma unroll
      for (int fr = 0; fr < 2; ++fr)
        #pragma unroll
        for (int j = 0; j < 4; ++j) {
          const int grow = r0 + fr * 16 + lk8 * 4 + j;
          #pragma unroll
          for (int fc = 0; fc < 2; ++fc) {
            const int gcol = c0 + fc * 16 + lrow;
            const float g = Gp[(size_t)grow * NV + gcol];
            if (g != 0.f) {
              const float* xr = X + ((size_t)grow << 6);
              const float* yr2 = Y + ((size_t)gcol << 6);
              const float dd = dot64(xr, yr2);
              const float x2 = dot64(xr, xr);
              const float y2 = dot64(yr2, yr2);
              otp += g * fmaxf(x2 + y2 - 2.f * dd, 0.f);
            }
          }
        }
      otw = wave_sum_all(otp);
    }
    if (lane == 0) W[OTP_OFF + t] = otw;
  }
  gbar(ctl);
  if (bid == 0) {
    float so = 0.f;
    for (int i = tid; i < NT; i += 256) so += W[OTP_OFF + i];
    so = wave_sum_dn(so);
    float sm = 0.f;
    for (int i = tid; i < NV; i += 256) {
      const float d = W[RS_OFF + i] - a[i];
      sm = fmaf(d, d, sm);
    }
    sm = wave_sum_dn(sm);
    if (lane == 0) { sred[wv] = so; serr[wv] = sm; }
    __syncthreads();
    if (tid == 0) {
      out[0] = sred[0] + sred[1] + sred[2] + sred[3];
      out[1] = (serr[0] + serr[1] + serr[2] + serr[3]) * (1.0f / (float)NV);
    }
  }
}

extern "C" void kernel_launch(void* const* d_in, const int* in_sizes, int n_in,
                              void* d_out, int out_size, void* d_ws, size_t ws_size,
                              hipStream_t stream) {
  const float* X = (const float*)d_in[0];   // source [4096,64]
  const float* Y = (const float*)d_in[1];   // target [4096,64]
  const float* a = (const float*)d_in[2];   // source_density [4096]
  const float* b = (const float*)d_in[3];   // target_density [4096]
  float* out = (float*)d_out;               // [ot_loss, marginal_loss]
  float* W = (float*)d_ws;

  k_prof<<<256, 256, 0, stream>>>(X, Y, a, b, W);
  k_screen<<<512, 256, 0, stream>>>(a, b, W);
  k_tail<<<GRID_T, 256, 0, stream>>>(X, Y, a, b, W, out);
}

// Round 9
// 87.333 us; speedup vs baseline: 1.1170x; 1.0647x over previous
//
#include <hip/hip_runtime.h>

// UOT mm_unbalanced(div='l2') on MI355X — profile-bound screen, 3 launches.
// K = max(5a_i+5b_j - M_ij, 0). Screen: per-group Cauchy-Schwarz with 16
// groups of 4 dims: M_ij >= X2_i + Y2_j - 2<u_i,v_j> (u,v = 16-dim norm
// profiles). Bound ~15 vs threshold 5(a+b)+margin ~0.014 => zero suspects
// for gaussian-scale data; any suspect pair is recomputed EXACTLY in fp32
// (cold), so correctness never depends on the data. Degenerate case (all
// K==0): plan==0 after iter 1, loop exits at iter 2 => ot=0,
// marginal_loss=mean(a^2).
// r9 fix vs r8: V-profiles stored TRANSPOSED [16][4096] so k_screen's
// inner-loop loads are lane-coalesced (r8 had 128B lane stride = 64-way
// transaction splintering, the round-2 pathology).

#define NV 4096
#define RM 5.0f
#define EPSF 1e-16f
#define STOP2 1e-30f   // (1e-15)^2
#define NITER 1000
#define MAGIC 0x5a17c0de
#define GRID_T 512
#define NT 16384       // 32x32 tiles (128 x 128)
#define MARGIN 1e-2f   // covers ref-M fp32 error (~1e-4) + screen fp error (~1e-4)

// W float offsets (producer-writes-before-consumer-reads; no pre-zero)
#define UP_OFF   0        // U profiles [4096][16] (row-major; broadcast reads)
#define VP_OFF   65536    // V profiles TRANSPOSED [16][4096]
#define X2_OFF   131072   // [4096] row sumsq (fp32)
#define Y2_OFF   135168   // [4096]
#define RA2_OFF  139264   // [128] per-32-row sum a^2
#define CB2_OFF  139392   // [128] per-32-col sum b^2
#define PA_OFF   139520   // [128] per-32-row sum a
#define PB_OFF   139648   // [128] per-32-col sum b
#define ERRT_OFF 147456   // [16384] per-tile err^2
#define ERRS_OFF 163840   // scalar err^2
#define OTP_OFF  180224   // [16384] per-tile ot partials
#define RSP_OFF  196608   // [16384][32] per-tile rowsums
#define CSP_OFF  720896   // [16384][32] per-tile colsums
#define RS_OFF   1245184  // [4096] reduced rowsums
#define CS_OFF   1249280  // [4096] reduced colsums
#define BMI_OFF  1253376  // int [16384] tile-nonzero bitmap
#define SUS_OFF  1269760  // int [16384] tile-suspect flags
#define NSUS_OFF 1286144  // int [0]=nsus, [1]=cnt, [2]=sense, [3]=magic
#define G_OFF    1310720  // [4096*4096] plan

typedef short bf16x8 __attribute__((ext_vector_type(8)));
typedef float f32x4  __attribute__((ext_vector_type(4)));
typedef unsigned short u16;

__device__ __forceinline__ float wave_sum_all(float v) {
  #pragma unroll
  for (int off = 1; off < 64; off <<= 1) v += __shfl_xor(v, off);
  return v;
}
__device__ __forceinline__ float red32_sum(float v) {
  #pragma unroll
  for (int off = 1; off < 32; off <<= 1) v += __shfl_xor(v, off);
  return v;
}
__device__ __forceinline__ float red32_max(float v) {
  #pragma unroll
  for (int off = 1; off < 32; off <<= 1) v = fmaxf(v, __shfl_xor(v, off));
  return v;
}
// output reduction kept bit-identical to validated rounds
__device__ __forceinline__ float wave_sum_dn(float v) {
  #pragma unroll
  for (int off = 32; off; off >>= 1) v += __shfl_down(v, off);
  return v;
}
__device__ __forceinline__ float dot64(const float* __restrict__ xr,
                                       const float* __restrict__ yr) {
  float d = 0.f;
  #pragma unroll 1
  for (int k = 0; k < 64; ++k) d = fmaf(xr[k], yr[k], d);
  return d;
}
__device__ __forceinline__ unsigned pack2(float x, float y) {
  return (__float_as_uint(x) >> 16) | (__float_as_uint(y) & 0xffff0000u);
}

// ================= k_prof: profiles + norms + group stats ================
// 256 blocks x 256. Block b: combined rows b*32..+32 (0..4095 = X, rest Y).
// Lane l: row l>>3, dims (l&7)*8..+8 = groups 2(l&7), 2(l&7)+1.
// Coalesced 32B/lane reads. X-profiles row-major; Y-profiles transposed.
__global__ __launch_bounds__(256) void k_prof(
    const float* __restrict__ X, const float* __restrict__ Y,
    const float* __restrict__ a, const float* __restrict__ bden,
    float* __restrict__ W) {
  const int bid = blockIdx.x, tid = threadIdx.x;
  const int lane = tid & 63, wvq = tid >> 6;
  const int lr = lane >> 3, l8 = lane & 7;
  const int R = bid * 32 + wvq * 8 + lr;         // combined row 0..8191
  const bool isX = (R < NV);
  const int row = isX ? R : R - NV;
  const float* src = (isX ? X : Y) + (size_t)row * 64;

  const float4 v0 = *(const float4*)(src + l8 * 8);
  const float4 v1 = *(const float4*)(src + l8 * 8 + 4);
  const float s0 = fmaf(v0.x, v0.x, fmaf(v0.y, v0.y, fmaf(v0.z, v0.z, v0.w * v0.w)));
  const float s1 = fmaf(v1.x, v1.x, fmaf(v1.y, v1.y, fmaf(v1.z, v1.z, v1.w * v1.w)));
  const float q0 = sqrtf(s0), q1 = sqrtf(s1);
  if (isX) {
    float2 uq; uq.x = q0; uq.y = q1;
    *(float2*)(W + UP_OFF + (size_t)row * 16 + l8 * 2) = uq;
  } else {
    W[VP_OFF + (2 * l8)     * NV + row] = q0;   // transposed [g][col]
    W[VP_OFF + (2 * l8 + 1) * NV + row] = q1;
  }
  float st = s0 + s1;
  st += __shfl_xor(st, 1); st += __shfl_xor(st, 2); st += __shfl_xor(st, 4);
  if (l8 == 0) W[(isX ? X2_OFF : Y2_OFF) + row] = st;

  // per-32-group stats of a (blocks 0..127) / b (128..255)
  if (wvq == 0 && lane < 32) {
    if (bid < 128) {
      const float av = a[bid * 32 + lane];
      const float r2 = red32_sum(av * av);
      const float pa = red32_sum(av);
      if (lane == 0) { W[RA2_OFF + bid] = r2; W[PA_OFF + bid] = pa; }
    } else {
      const float bv = bden[(bid - 128) * 32 + lane];
      const float c2 = red32_sum(bv * bv);
      const float pb = red32_sum(bv);
      if (lane == 0) { W[CB2_OFF + (bid - 128)] = c2; W[PB_OFF + (bid - 128)] = pb; }
    }
  }
  // zero suspect flags + counter (d_ws is poisoned each launch)
  if (tid < 64) ((int*)(W + SUS_OFF))[bid * 64 + tid] = 0;
  if (bid == 0 && tid == 64) ((int*)(W + NSUS_OFF))[0] = 0;
}

// ================= k_screen: 16-dim profile screen =====================
// 512 blocks x 256. Block: 8 U-rows in VGPRs (broadcast loads); wave wv:
// 1024-col span; lane: 2 adjacent cols x 8 passes. All v loads are float2
// at lane-stride 8B from the transposed VP => fully coalesced. Pure VALU.
// Non-suspect pair certifies X2+Y2-2<u,v> >= 5(a+b)+MARGIN => K==0 in ref.
__global__ __launch_bounds__(256, 2) void k_screen(
    const float* __restrict__ a, const float* __restrict__ bden,
    float* __restrict__ W) {
  const int tid = threadIdx.x, lane = tid & 63, wv = tid >> 6;
  const int rbase = blockIdx.x * 8;
  const int cbase = wv * 1024;
  const float* UP  = W + UP_OFF;
  const float* VPt = W + VP_OFF;
  int* sus  = (int*)(W + SUS_OFF);
  int* nsus = (int*)(W + NSUS_OFF);

  float u[8][16], ga[8];
  #pragma unroll
  for (int r = 0; r < 8; ++r) {
    const int row = rbase + r;
    #pragma unroll
    for (int q = 0; q < 4; ++q) {
      const float4 f = *(const float4*)(UP + (size_t)row * 16 + q * 4);
      u[r][q*4+0] = f.x; u[r][q*4+1] = f.y; u[r][q*4+2] = f.z; u[r][q*4+3] = f.w;
    }
    ga[r] = W[X2_OFF + row] - RM * a[row] - MARGIN;
  }

  #pragma unroll 1
  for (int k = 0; k < 8; ++k) {
    const int col0 = cbase + (lane << 1) + k * 128;
    float v0[16], v1[16];
    #pragma unroll
    for (int g = 0; g < 16; ++g) {
      const float2 vv = *(const float2*)(VPt + (size_t)g * NV + col0);
      v0[g] = vv.x; v1[g] = vv.y;
    }
    const float2 y2p = *(const float2*)(W + Y2_OFF + col0);
    const float2 bp  = *(const float2*)(bden + col0);
    const float d0 = y2p.x - RM * bp.x;
    const float d1 = y2p.y - RM * bp.y;

    unsigned smask = 0u;
    #pragma unroll
    for (int r = 0; r < 8; ++r) {
      float s0 = 0.f, s1 = 0.f;
      #pragma unroll
      for (int g = 0; g < 16; ++g) {
        s0 = fmaf(u[r][g], v0[g], s0);
        s1 = fmaf(u[r][g], v1[g], s1);
      }
      smask |= (2.f * s0 > ga[r] + d0) ? (1u << r) : 0u;
      smask |= (2.f * s1 > ga[r] + d1) ? (1u << (r + 8)) : 0u;
    }
    if (__builtin_expect(smask != 0u, 0)) {   // ~never: exact path handles
      #pragma unroll 1
      for (int r = 0; r < 8; ++r) {
        if (smask & (1u << r)) {
          atomicOr(&sus[((rbase + r) >> 5) * 128 + (col0 >> 5)], 1);
          atomicAdd(nsus, 1);
        }
        if (smask & (1u << (r + 8))) {
          atomicOr(&sus[((rbase + r) >> 5) * 128 + ((col0 + 1) >> 5)], 1);
          atomicAdd(nsus, 1);
        }
      }
    }
  }
}

// ---------- helpers for the cold general path (validated r7/r8) ----------
__device__ __forceinline__ void stage32(const float* __restrict__ src,
                                        u16 (*dst)[72], float* nrm, int lane) {
  #pragma unroll
  for (int it = 0; it < 8; ++it) {
    const int flat = lane + it * 64;
    const int r = flat >> 4, c4 = flat & 15;
    const float4 v = *(const float4*)(src + (size_t)r * 64 + c4 * 4);
    float p = fmaf(v.x, v.x, fmaf(v.y, v.y, fmaf(v.z, v.z, v.w * v.w)));
    p += __shfl_xor(p, 1); p += __shfl_xor(p, 2);
    p += __shfl_xor(p, 4); p += __shfl_xor(p, 8);
    if (c4 == 0) nrm[r] = p;
    uint2 w;
    w.x = pack2(v.x, v.y);
    w.y = pack2(v.z, v.w);
    *(uint2*)&dst[r][c4 * 4] = w;
  }
}
__device__ __forceinline__ void dots32(const u16 (*As)[72], const u16 (*Bs)[72],
                                       int lane, f32x4 acc[2][2]) {
  const int lrow = lane & 15, lk8 = lane >> 4;
  #pragma unroll
  for (int i = 0; i < 2; ++i)
    #pragma unroll
    for (int j = 0; j < 2; ++j)
      acc[i][j] = (f32x4){0.f, 0.f, 0.f, 0.f};
  #pragma unroll
  for (int ks = 0; ks < 2; ++ks) {
    bf16x8 af[2], bg[2];
    #pragma unroll
    for (int f = 0; f < 2; ++f) {
      af[f] = *(const bf16x8*)&As[f * 16 + lrow][ks * 32 + lk8 * 8];
      bg[f] = *(const bf16x8*)&Bs[f * 16 + lrow][ks * 32 + lk8 * 8];
    }
    #pragma unroll
    for (int fr = 0; fr < 2; ++fr)
      #pragma unroll
      for (int fc = 0; fc < 2; ++fc)
        acc[fr][fc] = __builtin_amdgcn_mfma_f32_16x16x32_bf16(
            af[fr], bg[fc], acc[fr][fc], 0, 0, 0);
  }
}
// sense-reversing device barrier (cold path only); ctl[1]=cnt [2]=sense [3]=magic
__device__ __forceinline__ void gbar(int* ctl) {
  __threadfence();
  __syncthreads();
  if (threadIdx.x == 0) {
    while (__hip_atomic_load(&ctl[3], __ATOMIC_ACQUIRE,
                             __HIP_MEMORY_SCOPE_AGENT) != (int)MAGIC)
      __builtin_amdgcn_s_sleep(8);
    const int sense = __hip_atomic_load(&ctl[2], __ATOMIC_ACQUIRE,
                                        __HIP_MEMORY_SCOPE_AGENT);
    const int old = __hip_atomic_fetch_add(&ctl[1], 1, __ATOMIC_ACQ_REL,
                                           __HIP_MEMORY_SCOPE_AGENT);
    if (old == GRID_T - 1) {
      __hip_atomic_store(&ctl[1], 0, __ATOMIC_RELAXED, __HIP_MEMORY_SCOPE_AGENT);
      __hip_atomic_store(&ctl[2], sense ^ 1, __ATOMIC_RELEASE,
                         __HIP_MEMORY_SCOPE_AGENT);
    } else {
      while (__hip_atomic_load(&ctl[2], __ATOMIC_ACQUIRE,
                               __HIP_MEMORY_SCOPE_AGENT) == sense)
        __builtin_amdgcn_s_sleep(16);
    }
  }
  __syncthreads();
  __threadfence();
}

// ================= k_tail: steer + exact + general =====================
__global__ __launch_bounds__(256, 2) void k_tail(
    const float* __restrict__ X, const float* __restrict__ Y,
    const float* __restrict__ a, const float* __restrict__ bden,
    float* __restrict__ W, float* __restrict__ out) {
  __shared__ u16 Aw[4][32][72], Bw[4][32][72];
  __shared__ float X2w[4][32], Y2w[4][32];
  __shared__ float serr[4], sred[4];

  const int bid = blockIdx.x, tid = threadIdx.x;
  const int lane = tid & 63, wv = tid >> 6;
  const int lrow = lane & 15, lk8 = lane >> 4, l32 = lane & 31;
  float* Gp = W + G_OFF;
  int* bmi  = (int*)(W + BMI_OFF);
  int* sus  = (int*)(W + SUS_OFF);
  int* ctl  = (int*)(W + NSUS_OFF);

  // ---- hot gate: zero suspects => plan == 0 exactly ----
  if (ctl[0] == 0) {
    if (bid == 0) {
      float s = 0.f;
      for (int i = tid; i < NV; i += 256) { const float d = a[i]; s = fmaf(d, d, s); }
      s = wave_sum_dn(s);
      if (lane == 0) serr[wv] = s;
      __syncthreads();
      if (tid == 0) {
        out[0] = 0.f;
        out[1] = (serr[0] + serr[1] + serr[2] + serr[3]) * (1.0f / (float)NV);
      }
    }
    return;
  }

  // =================== cold: suspects exist ============================
  if (bid == 0 && tid == 0) {   // arm barrier
    __hip_atomic_store(&ctl[1], 0, __ATOMIC_RELAXED, __HIP_MEMORY_SCOPE_AGENT);
    __hip_atomic_store(&ctl[2], 0, __ATOMIC_RELAXED, __HIP_MEMORY_SCOPE_AGENT);
    __hip_atomic_store(&ctl[3], (int)MAGIC, __ATOMIC_RELEASE,
                       __HIP_MEMORY_SCOPE_AGENT);
  }

  // ---- exact iteration-1: suspect tiles exact, clean tiles closed-form
  #pragma unroll 1
  for (int tt = 0; tt < 8; ++tt) {
    const int t = bid * 4 + wv + tt * 2048;
    const int by = t >> 7, bx = t & 127;
    if (!sus[t]) {
      if (lane == 0) {
        W[ERRT_OFF + t] = W[RA2_OFF + by] * W[CB2_OFF + bx];
        bmi[t] = 0;
      }
      continue;
    }
    const int r0 = by * 32, c0 = bx * 32;
    const int cl = lane & 31, h = lane >> 5;   // lane: col cl, row-half h
    float sa = W[PA_OFF + lane] + W[PA_OFF + lane + 64];
    sa = wave_sum_all(sa);
    float sb = W[PB_OFF + lane] + W[PB_OFF + lane + 64];
    sb = wave_sum_all(sb);
    const float bcl = bden[c0 + cl];
    const float y2c = W[Y2_OFF + c0 + cl];
    const float* yr = Y + (size_t)(c0 + cl) * 64;
    float csum = 0.f, errp = 0.f;
    int nzl = 0;
    #pragma unroll 1
    for (int r = 0; r < 16; ++r) {
      const int row = r0 + h * 16 + r;
      const float ar = a[row];
      const float x2r = W[X2_OFF + row];
      const float dx = dot64(X + (size_t)row * 64, yr);
      const float Mv = fmaxf(x2r + y2c - 2.f * dx, 0.f);
      const float Kv = fmaxf(RM * (ar + bcl) - Mv, 0.f);
      const float g0 = ar * bcl;
      const float gd = RM * ar * sb + RM * bcl * sa + EPSF;
      const float g = Kv * g0 / gd;
      Gp[(size_t)row * NV + c0 + cl] = g;
      const float dl = g - g0;
      errp += dl * dl;
      nzl |= (g != 0.f);
      csum += g;
      float rsv = red32_sum(g);               // rowsum over the 32 cols
      if (cl == 0) W[RSP_OFF + (size_t)t * 32 + h * 16 + r] = rsv;
    }
    csum += __shfl_xor(csum, 32);             // combine both row-halves
    if (h == 0) W[CSP_OFF + (size_t)t * 32 + cl] = csum;
    errp = wave_sum_all(errp);
    const int nz = (__ballot(nzl) != 0ull) ? 1 : 0;
    if (lane == 0) { W[ERRT_OFF + t] = errp; bmi[t] = nz; }
  }
  gbar(ctl);

  // ---- persistent loop: p = 2 .. (validated structure) ----
  int p = 2;
  while (true) {
    {
      const int sr = tid >> 5, j32 = tid & 31;
      const int r = bid * 8 + sr;
      const int byt = r >> 5, rl = r & 31;
      float vs = 0.f;
      for (int k = j32; k < 128; k += 32) {
        const int tt2 = byt * 128 + k;
        vs += bmi[tt2] ? W[RSP_OFF + (size_t)tt2 * 32 + rl] : 0.f;
      }
      vs = red32_sum(vs);
      if (j32 == 0) W[RS_OFF + r] = vs;
      float cs = 0.f;
      for (int k = j32; k < 128; k += 32) {
        const int tt2 = k * 128 + byt;
        cs += bmi[tt2] ? W[CSP_OFF + (size_t)tt2 * 32 + rl] : 0.f;
      }
      cs = red32_sum(cs);
      if (j32 == 0) W[CS_OFF + r] = cs;
    }
    if (bid == 0) {
      float e = 0.f;
      for (int i = tid; i < NT; i += 256) e += W[ERRT_OFF + i];
      e = wave_sum_all(e);
      if (lane == 0) sred[wv] = e;
      __syncthreads();
      if (tid == 0) W[ERRS_OFF] = sred[0] + sred[1] + sred[2] + sred[3];
    }
    gbar(ctl);
    const float errv = W[ERRS_OFF];
    if (errv <= STOP2 || p > NITER) break;

    #pragma unroll 1
    for (int tt = 0; tt < 8; ++tt) {
      const int t = bid * 4 + wv + tt * 2048;
      if (!bmi[t]) { if (lane == 0) W[ERRT_OFF + t] = 0.f; continue; }
      const int by = t >> 7, bx = t & 127;
      const int r0 = by * 32, c0 = bx * 32;

      const float av = a[r0 + l32], bv = bden[c0 + l32];
      const float Rv = W[RS_OFF + r0 + l32], Cv = W[CS_OFF + c0 + l32];

      stage32(X + (size_t)r0 * 64, Aw[wv], X2w[wv], lane);
      stage32(Y + (size_t)c0 * 64, Bw[wv], Y2w[wv], lane);
      f32x4 acc[2][2];
      dots32(Aw[wv], Bw[wv], lane, acc);

      float x2r[8], y2c[2], bcf[2], Ccf[2];
      #pragma unroll
      for (int fr = 0; fr < 2; ++fr)
        #pragma unroll
        for (int j = 0; j < 4; ++j)
          x2r[fr * 4 + j] = X2w[wv][fr * 16 + lk8 * 4 + j];
      #pragma unroll
      for (int fc = 0; fc < 2; ++fc) {
        y2c[fc] = Y2w[wv][fc * 16 + lrow];
        bcf[fc] = __shfl(bv, fc * 16 + lrow);
        Ccf[fc] = __shfl(Cv, fc * 16 + lrow);
      }
      const float x2lv = X2w[wv][l32], y2lv = Y2w[wv][l32];
      const float amax = red32_max(av), bmax = red32_max(bv);
      const float x2m = red32_max(x2lv), y2m = red32_max(y2lv);
      const float Cw = RM * (amax + bmax) + 0.02f * sqrtf(x2m * y2m) + 0.05f;

      float errp = 0.f, csum[2] = {0.f, 0.f};
      int nzl = 0;
      float rs8[8];
      #pragma unroll
      for (int fr = 0; fr < 2; ++fr)
        #pragma unroll
        for (int j = 0; j < 4; ++j) {
          const int ridx = fr * 16 + lk8 * 4 + j;
          const float ar = __shfl(av, ridx);
          const float Rr = __shfl(Rv, ridx);
          const int grow = r0 + ridx;
          float rsum = 0.f;
          #pragma unroll
          for (int fc = 0; fc < 2; ++fc) {
            const int gcol = c0 + fc * 16 + lrow;
            const float g = Gp[(size_t)grow * NV + gcol];
            float Mv = fmaf(-2.f, acc[fr][fc][j], x2r[fr * 4 + j] + y2c[fc]);
            if (Mv < Cw) {
              const float dx = dot64(X + ((size_t)grow << 6),
                                     Y + ((size_t)gcol << 6));
              Mv = x2r[fr * 4 + j] + y2c[fc] - 2.f * dx;
            }
            Mv = fmaxf(Mv, 0.f);
            const float Kv = fmaxf(RM * (ar + bcf[fc]) - Mv, 0.f);
            const float gd = RM * Rr + RM * Ccf[fc] + EPSF;
            const float gn = Kv * g / gd;
            acc[fr][fc][j] = gn;
            const float dl = gn - g;
            errp += dl * dl;
            nzl |= (gn != 0.f);
            rsum += gn;
            csum[fc] += gn;
          }
          float rv = rsum;
          rv += __shfl_xor(rv, 1); rv += __shfl_xor(rv, 2);
          rv += __shfl_xor(rv, 4); rv += __shfl_xor(rv, 8);
          rs8[fr * 4 + j] = rv;
        }
      const int nz = (__ballot(nzl) != 0ull) ? 1 : 0;
      #pragma unroll
      for (int fr = 0; fr < 2; ++fr)
        #pragma unroll
        for (int j = 0; j < 4; ++j) {
          const int ridx = fr * 16 + lk8 * 4 + j;
          const int grow = r0 + ridx;
          #pragma unroll
          for (int fc = 0; fc < 2; ++fc)
            Gp[(size_t)grow * NV + c0 + fc * 16 + lrow] = acc[fr][fc][j];
          if (lrow == 0) W[RSP_OFF + (size_t)t * 32 + ridx] = rs8[fr * 4 + j];
        }
      #pragma unroll
      for (int fc = 0; fc < 2; ++fc) {
        float cv = csum[fc];
        cv += __shfl_xor(cv, 16); cv += __shfl_xor(cv, 32);
        if (lane < 16) W[CSP_OFF + (size_t)t * 32 + fc * 16 + lrow] = cv;
      }
      errp = wave_sum_all(errp);
      if (lane == 0) {
        W[ERRT_OFF + t] = errp;
        bmi[t] = nz;
      }
    }
    gbar(ctl);
    ++p;
  }

  // final: ot = sum(G*M) over nonzero tiles (exact dots); marg = RS
  #pragma unroll 1
  for (int tt = 0; tt < 8; ++tt) {
    const int t = bid * 4 + wv + tt * 2048;
    float otw = 0.f;
    if (bmi[t]) {
      const int by = t >> 7, bx = t & 127;
      const int r0 = by * 32, c0 = bx * 32;
      float otp = 0.f;
      #pragma unroll
      for (int fr = 0; fr < 2; ++fr)
        #pragma unroll
        for (int j = 0; j < 4; ++j) {
          const int grow = r0 + fr * 16 + lk8 * 4 + j;
          #pragma unroll
          for (int fc = 0; fc < 2; ++fc) {
            const int gcol = c0 + fc * 16 + lrow;
            const float g = Gp[(size_t)grow * NV + gcol];
            if (g != 0.f) {
              const float* xr = X + ((size_t)grow << 6);
              const float* yr2 = Y + ((size_t)gcol << 6);
              const float dd = dot64(xr, yr2);
              const float x2 = dot64(xr, xr);
              const float y2 = dot64(yr2, yr2);
              otp += g * fmaxf(x2 + y2 - 2.f * dd, 0.f);
            }
          }
        }
      otw = wave_sum_all(otp);
    }
    if (lane == 0) W[OTP_OFF + t] = otw;
  }
  gbar(ctl);
  if (bid == 0) {
    float so = 0.f;
    for (int i = tid; i < NT; i += 256) so += W[OTP_OFF + i];
    so = wave_sum_dn(so);
    float sm = 0.f;
    for (int i = tid; i < NV; i += 256) {
      const float d = W[RS_OFF + i] - a[i];
      sm = fmaf(d, d, sm);
    }
    sm = wave_sum_dn(sm);
    if (lane == 0) { sred[wv] = so; serr[wv] = sm; }
    __syncthreads();
    if (tid == 0) {
      out[0] = sred[0] + sred[1] + sred[2] + sred[3];
      out[1] = (serr[0] + serr[1] + serr[2] + serr[3]) * (1.0f / (float)NV);
    }
  }
}

extern "C" void kernel_launch(void* const* d_in, const int* in_sizes, int n_in,
                              void* d_out, int out_size, void* d_ws, size_t ws_size,
                              hipStream_t stream) {
  const float* X = (const float*)d_in[0];   // source [4096,64]
  const float* Y = (const float*)d_in[1];   // target [4096,64]
  const float* a = (const float*)d_in[2];   // source_density [4096]
  const float* b = (const float*)d_in[3];   // target_density [4096]
  float* out = (float*)d_out;               // [ot_loss, marginal_loss]
  float* W = (float*)d_ws;

  k_prof<<<256, 256, 0, stream>>>(X, Y, a, b, W);
  k_screen<<<512, 256, 0, stream>>>(a, b, W);
  k_tail<<<GRID_T, 256, 0, stream>>>(X, Y, a, b, W, out);
}